// Round 1
// baseline (1306.228 us; speedup 1.0000x reference)
//
#include <hip/hip_runtime.h>
#include <math.h>

#define SEQ  4096
#define DIN  1024
#define DOUT 1024

#define BM 64
#define BN 64
#define BK 16

// C[M,N] = scale * A[M,K] @ op(B)
// TRANS==0: B is [K,N] row-major (op(B)=B)
// TRANS==1: B is [N,K] row-major (op(B)=B^T), i.e. C = A @ B^T
template <int TRANS>
__global__ __launch_bounds__(256) void gemm_f32(const float* __restrict__ A,
                                                const float* __restrict__ B,
                                                float* __restrict__ C,
                                                int M, int N, int K, float scale) {
    // K-major LDS tiles; row stride 68 floats = 272 B (16B-aligned, odd/16 so
    // float4 reads across lanes alias banks at most 2-way (free on CDNA4).
    __shared__ float As[BK][BM + 4];
    __shared__ float Bs[BK][BN + 4];

    const int tid = threadIdx.x;
    const int tx = tid & 15;   // micro-tile col group
    const int ty = tid >> 4;   // micro-tile row group
    const int rowBase = blockIdx.y * BM;
    const int colBase = blockIdx.x * BN;

    // A tile load indices: 64x16 floats = 256 float4, one per thread
    const int ar = tid >> 2;          // 0..63 (row in tile)
    const int ac = (tid & 3) << 2;    // 0,4,8,12 (k within tile)
    // B tile load indices
    const int br0 = tid >> 4;         // TRANS==0: 0..15 (k row)
    const int bc0 = (tid & 15) << 2;  // TRANS==0: col 0..60
    const int bn1 = tid >> 2;         // TRANS==1: 0..63 (B row = C col)
    const int bk1 = (tid & 3) << 2;   // TRANS==1: k within tile

    float acc[4][4] = {};

    for (int k0 = 0; k0 < K; k0 += BK) {
        // --- stage A tile (transposed into K-major) ---
        float4 av = *(const float4*)(A + (size_t)(rowBase + ar) * K + (k0 + ac));
        As[ac + 0][ar] = av.x;
        As[ac + 1][ar] = av.y;
        As[ac + 2][ar] = av.z;
        As[ac + 3][ar] = av.w;
        // --- stage B tile ---
        if (TRANS == 0) {
            float4 bv = *(const float4*)(B + (size_t)(k0 + br0) * N + (colBase + bc0));
            *(float4*)&Bs[br0][bc0] = bv;
        } else {
            float4 bv = *(const float4*)(B + (size_t)(colBase + bn1) * K + (k0 + bk1));
            Bs[bk1 + 0][bn1] = bv.x;
            Bs[bk1 + 1][bn1] = bv.y;
            Bs[bk1 + 2][bn1] = bv.z;
            Bs[bk1 + 3][bn1] = bv.w;
        }
        __syncthreads();

#pragma unroll
        for (int kk = 0; kk < BK; ++kk) {
            float4 a4 = *(const float4*)&As[kk][ty << 2];
            float4 b4 = *(const float4*)&Bs[kk][tx << 2];
            float a[4] = {a4.x, a4.y, a4.z, a4.w};
            float b[4] = {b4.x, b4.y, b4.z, b4.w};
#pragma unroll
            for (int i = 0; i < 4; ++i)
#pragma unroll
                for (int j = 0; j < 4; ++j)
                    acc[i][j] = fmaf(a[i], b[j], acc[i][j]);
        }
        __syncthreads();
    }

#pragma unroll
    for (int i = 0; i < 4; ++i) {
        float4 o;
        o.x = acc[i][0] * scale;
        o.y = acc[i][1] * scale;
        o.z = acc[i][2] * scale;
        o.w = acc[i][3] * scale;
        *(float4*)(C + (size_t)(rowBase + (ty << 2) + i) * N + colBase + (tx << 2)) = o;
    }
}

// In-place row softmax over S[SEQ, SEQ]; one block (256 thr) per row,
// 16 elements per thread held in registers (load once, write once).
__global__ __launch_bounds__(256) void softmax_rows(float* __restrict__ S) {
    __shared__ float redmax[4];
    __shared__ float redsum[4];
    const int tid = threadIdx.x;
    float* rowp = S + (size_t)blockIdx.x * SEQ;

    float4 v[4];
#pragma unroll
    for (int i = 0; i < 4; ++i)
        v[i] = *(const float4*)(rowp + i * 1024 + (tid << 2));

    float m = -INFINITY;
#pragma unroll
    for (int i = 0; i < 4; ++i)
        m = fmaxf(m, fmaxf(fmaxf(v[i].x, v[i].y), fmaxf(v[i].z, v[i].w)));
#pragma unroll
    for (int off = 32; off > 0; off >>= 1) m = fmaxf(m, __shfl_xor(m, off));
    if ((tid & 63) == 0) redmax[tid >> 6] = m;
    __syncthreads();
    m = fmaxf(fmaxf(redmax[0], redmax[1]), fmaxf(redmax[2], redmax[3]));

    float s = 0.f;
#pragma unroll
    for (int i = 0; i < 4; ++i) {
        v[i].x = expf(v[i].x - m); s += v[i].x;
        v[i].y = expf(v[i].y - m); s += v[i].y;
        v[i].z = expf(v[i].z - m); s += v[i].z;
        v[i].w = expf(v[i].w - m); s += v[i].w;
    }
#pragma unroll
    for (int off = 32; off > 0; off >>= 1) s += __shfl_xor(s, off);
    if ((tid & 63) == 0) redsum[tid >> 6] = s;
    __syncthreads();
    s = redsum[0] + redsum[1] + redsum[2] + redsum[3];

    const float inv = 1.0f / s;
#pragma unroll
    for (int i = 0; i < 4; ++i) {
        v[i].x *= inv; v[i].y *= inv; v[i].z *= inv; v[i].w *= inv;
        *(float4*)(rowp + i * 1024 + (tid << 2)) = v[i];
    }
}

extern "C" void kernel_launch(void* const* d_in, const int* in_sizes, int n_in,
                              void* d_out, int out_size, void* d_ws, size_t ws_size,
                              hipStream_t stream) {
    const float* x  = (const float*)d_in[0];  // [SEQ, DIN]
    const float* wq = (const float*)d_in[1];  // [DIN, DOUT]
    const float* wk = (const float*)d_in[2];
    const float* wv = (const float*)d_in[3];
    float* out = (float*)d_out;               // [SEQ, DOUT]

    // Workspace layout (needs 112 MB): Q,K,V 16 MB each + S 64 MB
    float* Q = (float*)d_ws;
    float* K = Q + (size_t)SEQ * DOUT;
    float* V = K + (size_t)SEQ * DOUT;
    float* S = V + (size_t)SEQ * DOUT;

    dim3 blk(256);

    // QKV projections: [SEQ,DIN] @ [DIN,DOUT]
    dim3 gproj(DOUT / BN, SEQ / BM);
    gemm_f32<0><<<gproj, blk, 0, stream>>>(x, wq, Q, SEQ, DOUT, DIN, 1.0f);
    gemm_f32<0><<<gproj, blk, 0, stream>>>(x, wk, K, SEQ, DOUT, DIN, 1.0f);
    gemm_f32<0><<<gproj, blk, 0, stream>>>(x, wv, V, SEQ, DOUT, DIN, 1.0f);

    // Scores: S = (Q @ K^T) / sqrt(DOUT)
    dim3 gscore(SEQ / BN, SEQ / BM);
    gemm_f32<1><<<gscore, blk, 0, stream>>>(Q, K, S, SEQ, SEQ, DOUT, 1.0f / 32.0f);

    // Row softmax in place
    softmax_rows<<<SEQ, blk, 0, stream>>>(S);

    // Context: out = P @ V
    dim3 gctx(DOUT / BN, SEQ / BM);
    gemm_f32<0><<<gctx, blk, 0, stream>>>(S, V, out, SEQ, DOUT, SEQ, 1.0f);
}

// Round 4
// 569.289 us; speedup vs baseline: 2.2945x; 2.2945x over previous
//
#include <hip/hip_runtime.h>
#include <hip/hip_fp16.h>
#include <math.h>

#define SEQ    4096
#define DMODEL 1024

typedef _Float16 half8  __attribute__((ext_vector_type(8)));
typedef _Float16 half4v __attribute__((ext_vector_type(4)));
typedef float    floatx4 __attribute__((ext_vector_type(4)));

// ---------------------------------------------------------------------------
// Split helpers: fp32 -> hi/lo fp16 (a = hi + lo, |lo| <= 2^-11 |a|)
// ---------------------------------------------------------------------------
__device__ inline void split_val(float v, _Float16& h, _Float16& l) {
    _Float16 hh = (_Float16)v;
    h = hh;
    l = (_Float16)(v - (float)hh);
}

// ---------------------------------------------------------------------------
// Elementwise split: in[n] fp32 -> hi[n], lo[n] fp16  (n multiple of 4)
// ---------------------------------------------------------------------------
__global__ __launch_bounds__(256) void split_f32(const float* __restrict__ in,
                                                 _Float16* __restrict__ hi,
                                                 _Float16* __restrict__ lo, int n4) {
    int i = blockIdx.x * 256 + threadIdx.x;
    for (; i < n4; i += gridDim.x * 256) {
        floatx4 v = *(const floatx4*)(in + 4 * (size_t)i);
        half4v h, l;
#pragma unroll
        for (int j = 0; j < 4; ++j) {
            _Float16 hh = (_Float16)v[j];
            _Float16 ll = (_Float16)(v[j] - (float)hh);
            h[j] = hh;
            l[j] = ll;
        }
        *(half4v*)(hi + 4 * (size_t)i) = h;
        *(half4v*)(lo + 4 * (size_t)i) = l;
    }
}

// ---------------------------------------------------------------------------
// Transpose + split: w[1024][1024] fp32 -> thi/tlo[1024][1024] fp16 = w^T
// block 256 (32x8), grid (32,32)
// ---------------------------------------------------------------------------
__global__ __launch_bounds__(256) void transpose_split(const float* __restrict__ w,
                                                       _Float16* __restrict__ thi,
                                                       _Float16* __restrict__ tlo) {
    __shared__ float tile[32][33];
    const int tx = threadIdx.x & 31, ty = threadIdx.x >> 5;
    const int c0 = blockIdx.x * 32, r0 = blockIdx.y * 32;
#pragma unroll
    for (int j = 0; j < 4; ++j)
        tile[ty * 4 + j][tx] = w[(size_t)(r0 + ty * 4 + j) * DMODEL + c0 + tx];
    __syncthreads();
#pragma unroll
    for (int j = 0; j < 4; ++j) {
        float v = tile[tx][ty * 4 + j];
        size_t idx = (size_t)(c0 + ty * 4 + j) * DMODEL + r0 + tx;
        _Float16 h, l;
        split_val(v, h, l);
        thi[idx] = h;
        tlo[idx] = l;
    }
}

// ---------------------------------------------------------------------------
// Split-precision fp16 MFMA GEMM:
//   C[M][N] = scale * (Ahi+Alo)[M][K] @ (Bhi+Blo)[N][K]^T
// Both operands K-major, row strides lda/ldb in elements.
// OUT_SPLIT==0: write fp32 to Cf.  OUT_SPLIT==1: write hi/lo fp16 to Chi/Clo.
// Tile 128x128, BK=32, 256 threads = 4 waves (2x2), wave tile 64x64.
// LDS chunks XOR-swizzled on the GLOBAL side so global_load_lds stays
// lane-contiguous and frag ds_reads are only 2-way bank-aliased (free).
// ---------------------------------------------------------------------------
template <int OUT_SPLIT>
__global__ __launch_bounds__(256) void gemm_mfma(
    const _Float16* __restrict__ Ahi, const _Float16* __restrict__ Alo, int lda,
    const _Float16* __restrict__ Bhi, const _Float16* __restrict__ Blo, int ldb,
    float* __restrict__ Cf, _Float16* __restrict__ Chi, _Float16* __restrict__ Clo,
    int N, int K, float scale) {
    __shared__ _Float16 Ah[128][32];
    __shared__ _Float16 Al[128][32];
    __shared__ _Float16 Bh[128][32];
    __shared__ _Float16 Bl[128][32];

    const int tid = threadIdx.x;
    const int lane = tid & 63;
    const int w = tid >> 6;            // wave 0..3
    const int wm = (w >> 1) * 64;      // wave row offset within tile
    const int wn = (w & 1) * 64;       // wave col offset within tile

    const int rowA0 = blockIdx.y * 128;
    const int colB0 = blockIdx.x * 128;

    // ---- staging geometry: one glds instr = 64 lanes x 16 B = 16 rows x 64 B
    const int sr = lane >> 2;   // row within 16-row group
    const int sc = lane & 3;    // chunk slot
    const int r0 = w * 32 + sr;
    const int r1 = r0 + 16;
    const int cg0 = sc ^ ((r0 >> 1) & 3);   // global chunk for slot sc, row r0
    const int cg1 = sc ^ ((r1 >> 1) & 3);

    const char* gp[8];
    gp[0] = (const char*)(Ahi + (size_t)(rowA0 + r0) * lda) + cg0 * 16;
    gp[1] = (const char*)(Ahi + (size_t)(rowA0 + r1) * lda) + cg1 * 16;
    gp[2] = (const char*)(Alo + (size_t)(rowA0 + r0) * lda) + cg0 * 16;
    gp[3] = (const char*)(Alo + (size_t)(rowA0 + r1) * lda) + cg1 * 16;
    gp[4] = (const char*)(Bhi + (size_t)(colB0 + r0) * ldb) + cg0 * 16;
    gp[5] = (const char*)(Bhi + (size_t)(colB0 + r1) * ldb) + cg1 * 16;
    gp[6] = (const char*)(Blo + (size_t)(colB0 + r0) * ldb) + cg0 * 16;
    gp[7] = (const char*)(Blo + (size_t)(colB0 + r1) * ldb) + cg1 * 16;

    _Float16* lp[8] = {
        &Ah[w * 32][0], &Ah[w * 32 + 16][0],
        &Al[w * 32][0], &Al[w * 32 + 16][0],
        &Bh[w * 32][0], &Bh[w * 32 + 16][0],
        &Bl[w * 32][0], &Bl[w * 32 + 16][0],
    };

    // ---- fragment read geometry
    const int fm = lane & 15;               // row within 16x16 tile
    const int fq = lane >> 4;               // k-quad
    const int ck = ((fq ^ ((fm >> 1) & 3)) * 8);  // swizzled k-chunk offset (halfs)

    floatx4 acc[4][4] = {};

    for (int k0 = 0; k0 < K; k0 += 32) {
#pragma unroll
        for (int t = 0; t < 8; ++t)
            __builtin_amdgcn_global_load_lds(
                (const __attribute__((address_space(1))) void*)gp[t],
                (__attribute__((address_space(3))) void*)lp[t], 16, 0, 0);
#pragma unroll
        for (int t = 0; t < 8; ++t) gp[t] += 64;   // advance 32 halfs along K
        __syncthreads();

        half8 ahv[4], bhv[4], blv[4], alv[4];
#pragma unroll
        for (int i = 0; i < 4; ++i) {
            ahv[i] = *(const half8*)&Ah[wm + i * 16 + fm][ck];
            bhv[i] = *(const half8*)&Bh[wn + i * 16 + fm][ck];
        }
#pragma unroll
        for (int i = 0; i < 4; ++i)
#pragma unroll
            for (int j = 0; j < 4; ++j)
                acc[i][j] = __builtin_amdgcn_mfma_f32_16x16x32_f16(ahv[i], bhv[j], acc[i][j], 0, 0, 0);
#pragma unroll
        for (int i = 0; i < 4; ++i) blv[i] = *(const half8*)&Bl[wn + i * 16 + fm][ck];
#pragma unroll
        for (int i = 0; i < 4; ++i)
#pragma unroll
            for (int j = 0; j < 4; ++j)
                acc[i][j] = __builtin_amdgcn_mfma_f32_16x16x32_f16(ahv[i], blv[j], acc[i][j], 0, 0, 0);
#pragma unroll
        for (int i = 0; i < 4; ++i) alv[i] = *(const half8*)&Al[wm + i * 16 + fm][ck];
#pragma unroll
        for (int i = 0; i < 4; ++i)
#pragma unroll
            for (int j = 0; j < 4; ++j)
                acc[i][j] = __builtin_amdgcn_mfma_f32_16x16x32_f16(alv[i], bhv[j], acc[i][j], 0, 0, 0);
        __syncthreads();
    }

    // ---- epilogue: C/D layout col=lane&15, row=quad*4+reg
#pragma unroll
    for (int i = 0; i < 4; ++i) {
        const int growb = rowA0 + wm + i * 16 + fq * 4;
#pragma unroll
        for (int j = 0; j < 4; ++j) {
            const int gcol = colB0 + wn + j * 16 + fm;
#pragma unroll
            for (int r = 0; r < 4; ++r) {
                float v = acc[i][j][r] * scale;
                size_t idx = (size_t)(growb + r) * N + gcol;
                if (OUT_SPLIT) {
                    _Float16 h, l;
                    split_val(v, h, l);
                    Chi[idx] = h;
                    Clo[idx] = l;
                } else {
                    Cf[idx] = v;
                }
            }
        }
    }
}

// ---------------------------------------------------------------------------
// Row softmax over S[SEQ][SEQ] fp32, writing P split into the SAME storage:
// row i bytes [0,8K) = P_hi fp16, [8K,16K) = P_lo fp16.
// One block (256 thr) per row; whole row lives in registers before any write.
// ---------------------------------------------------------------------------
__global__ __launch_bounds__(256) void softmax_rows_split(float* __restrict__ S) {
    __shared__ float redmax[4];
    __shared__ float redsum[4];
    const int tid = threadIdx.x;
    float* rowp = S + (size_t)blockIdx.x * SEQ;

    float4 v[4];
#pragma unroll
    for (int i = 0; i < 4; ++i)
        v[i] = *(const float4*)(rowp + i * 1024 + (tid << 2));

    float m = -INFINITY;
#pragma unroll
    for (int i = 0; i < 4; ++i)
        m = fmaxf(m, fmaxf(fmaxf(v[i].x, v[i].y), fmaxf(v[i].z, v[i].w)));
#pragma unroll
    for (int off = 32; off > 0; off >>= 1) m = fmaxf(m, __shfl_xor(m, off));
    if ((tid & 63) == 0) redmax[tid >> 6] = m;
    __syncthreads();   // also guarantees ALL loads complete before any write below
    m = fmaxf(fmaxf(redmax[0], redmax[1]), fmaxf(redmax[2], redmax[3]));

    float s = 0.f;
#pragma unroll
    for (int i = 0; i < 4; ++i) {
        v[i].x = expf(v[i].x - m); s += v[i].x;
        v[i].y = expf(v[i].y - m); s += v[i].y;
        v[i].z = expf(v[i].z - m); s += v[i].z;
        v[i].w = expf(v[i].w - m); s += v[i].w;
    }
#pragma unroll
    for (int off = 32; off > 0; off >>= 1) s += __shfl_xor(s, off);
    if ((tid & 63) == 0) redsum[tid >> 6] = s;
    __syncthreads();
    s = redsum[0] + redsum[1] + redsum[2] + redsum[3];

    const float inv = 1.0f / s;
    _Float16* hp = (_Float16*)rowp;
    _Float16* lq = hp + 4096;
#pragma unroll
    for (int i = 0; i < 4; ++i) {
        float f[4] = {v[i].x * inv, v[i].y * inv, v[i].z * inv, v[i].w * inv};
        half4v h, l;
#pragma unroll
        for (int j = 0; j < 4; ++j) {
            _Float16 hh = (_Float16)f[j];
            _Float16 ll = (_Float16)(f[j] - (float)hh);
            h[j] = hh;
            l[j] = ll;
        }
        *(half4v*)(hp + i * 1024 + (tid << 2)) = h;
        *(half4v*)(lq + i * 1024 + (tid << 2)) = l;
    }
}

// ---------------------------------------------------------------------------
// Workspace layout (112 MB total, same footprint as passing round-1):
//  [0,64M)   S fp32 4096x4096  (after softmax: per-row P_hi|P_lo fp16)
//    [0,8M)   x_hi   (dead before S written)
//    [8,16M)  x_lo
//    [16,28M) wqT/wkT/wvT hi+lo (6 x 2MB)
//  [64,72M)  Q_hi   [72,80M) Q_lo   [80,88M) K_hi   [88,96M) K_lo
//  [96,104M) VT_hi  [104,112M) VT_lo
// ---------------------------------------------------------------------------
extern "C" void kernel_launch(void* const* d_in, const int* in_sizes, int n_in,
                              void* d_out, int out_size, void* d_ws, size_t ws_size,
                              hipStream_t stream) {
    const float* x  = (const float*)d_in[0];
    const float* wq = (const float*)d_in[1];
    const float* wk = (const float*)d_in[2];
    const float* wv = (const float*)d_in[3];
    float* out = (float*)d_out;

    char* base = (char*)d_ws;
    const size_t MB = 1u << 20;
    float*    S      = (float*)base;
    _Float16* x_hi   = (_Float16*)(base + 0 * MB);
    _Float16* x_lo   = (_Float16*)(base + 8 * MB);
    _Float16* wqT_hi = (_Float16*)(base + 16 * MB);
    _Float16* wqT_lo = (_Float16*)(base + 18 * MB);
    _Float16* wkT_hi = (_Float16*)(base + 20 * MB);
    _Float16* wkT_lo = (_Float16*)(base + 22 * MB);
    _Float16* wvT_hi = (_Float16*)(base + 24 * MB);
    _Float16* wvT_lo = (_Float16*)(base + 26 * MB);
    _Float16* Q_hi   = (_Float16*)(base + 64 * MB);
    _Float16* Q_lo   = (_Float16*)(base + 72 * MB);
    _Float16* K_hi   = (_Float16*)(base + 80 * MB);
    _Float16* K_lo   = (_Float16*)(base + 88 * MB);
    _Float16* VT_hi  = (_Float16*)(base + 96 * MB);
    _Float16* VT_lo  = (_Float16*)(base + 104 * MB);

    // 1) splits
    split_f32<<<4096, 256, 0, stream>>>(x, x_hi, x_lo, SEQ * DMODEL / 4);
    dim3 tg(32, 32);
    transpose_split<<<tg, 256, 0, stream>>>(wq, wqT_hi, wqT_lo);
    transpose_split<<<tg, 256, 0, stream>>>(wk, wkT_hi, wkT_lo);
    transpose_split<<<tg, 256, 0, stream>>>(wv, wvT_hi, wvT_lo);

    // 2) projections (split fp16 outputs)
    dim3 gqk(DMODEL / 128, SEQ / 128);   // (8,32)
    gemm_mfma<1><<<gqk, 256, 0, stream>>>(x_hi, x_lo, DMODEL, wqT_hi, wqT_lo, DMODEL,
                                          nullptr, Q_hi, Q_lo, DMODEL, DMODEL, 1.0f);
    gemm_mfma<1><<<gqk, 256, 0, stream>>>(x_hi, x_lo, DMODEL, wkT_hi, wkT_lo, DMODEL,
                                          nullptr, K_hi, K_lo, DMODEL, DMODEL, 1.0f);
    // V^T = wv^T @ x^T : M=1024, N=4096, K=1024 (both operands K-major already)
    dim3 gvt(SEQ / 128, DMODEL / 128);   // (32,8)
    gemm_mfma<1><<<gvt, 256, 0, stream>>>(wvT_hi, wvT_lo, DMODEL, x_hi, x_lo, DMODEL,
                                          nullptr, VT_hi, VT_lo, SEQ, DMODEL, 1.0f);

    // 3) scores: S = (Q @ K^T) / 32
    dim3 gs(SEQ / 128, SEQ / 128);       // (32,32)
    gemm_mfma<0><<<gs, 256, 0, stream>>>(Q_hi, Q_lo, DMODEL, K_hi, K_lo, DMODEL,
                                         S, nullptr, nullptr, SEQ, DMODEL, 1.0f / 32.0f);

    // 4) softmax + split P in place
    softmax_rows_split<<<SEQ, 256, 0, stream>>>(S);

    // 5) out = P @ V : A = P (hi/lo interleaved per row, stride 8192 halfs), B = V^T
    dim3 go(DMODEL / 128, SEQ / 128);    // (8,32)
    gemm_mfma<0><<<go, 256, 0, stream>>>((_Float16*)S, (_Float16*)S + 4096, 2 * SEQ,
                                         VT_hi, VT_lo, SEQ,
                                         out, nullptr, nullptr, DMODEL, SEQ, 1.0f);
}

// Round 5
// 441.182 us; speedup vs baseline: 2.9607x; 1.2904x over previous
//
#include <hip/hip_runtime.h>
#include <hip/hip_fp16.h>
#include <math.h>

#define SEQ    4096
#define DMODEL 1024

typedef _Float16 half8  __attribute__((ext_vector_type(8)));
typedef _Float16 half4v __attribute__((ext_vector_type(4)));
typedef float    floatx4 __attribute__((ext_vector_type(4)));

// ---------------------------------------------------------------------------
// Split helpers: fp32 -> hi/lo fp16 (a = hi + lo, |lo| <= 2^-11 |a|)
// ---------------------------------------------------------------------------
__device__ inline void split_val(float v, _Float16& h, _Float16& l) {
    _Float16 hh = (_Float16)v;
    h = hh;
    l = (_Float16)(v - (float)hh);
}

// ---------------------------------------------------------------------------
// Elementwise split: in[n] fp32 -> hi[n], lo[n] fp16  (n multiple of 4)
// ---------------------------------------------------------------------------
__global__ __launch_bounds__(256) void split_f32(const float* __restrict__ in,
                                                 _Float16* __restrict__ hi,
                                                 _Float16* __restrict__ lo, int n4) {
    int i = blockIdx.x * 256 + threadIdx.x;
    for (; i < n4; i += gridDim.x * 256) {
        floatx4 v = *(const floatx4*)(in + 4 * (size_t)i);
        half4v h, l;
#pragma unroll
        for (int j = 0; j < 4; ++j) {
            _Float16 hh = (_Float16)v[j];
            _Float16 ll = (_Float16)(v[j] - (float)hh);
            h[j] = hh;
            l[j] = ll;
        }
        *(half4v*)(hi + 4 * (size_t)i) = h;
        *(half4v*)(lo + 4 * (size_t)i) = l;
    }
}

// ---------------------------------------------------------------------------
// Transpose + split: w[1024][1024] fp32 -> thi/tlo[1024][1024] fp16 = w^T
// ---------------------------------------------------------------------------
__global__ __launch_bounds__(256) void transpose_split(const float* __restrict__ w,
                                                       _Float16* __restrict__ thi,
                                                       _Float16* __restrict__ tlo) {
    __shared__ float tile[32][33];
    const int tx = threadIdx.x & 31, ty = threadIdx.x >> 5;
    const int c0 = blockIdx.x * 32, r0 = blockIdx.y * 32;
#pragma unroll
    for (int j = 0; j < 4; ++j)
        tile[ty * 4 + j][tx] = w[(size_t)(r0 + ty * 4 + j) * DMODEL + c0 + tx];
    __syncthreads();
#pragma unroll
    for (int j = 0; j < 4; ++j) {
        float v = tile[tx][ty * 4 + j];
        size_t idx = (size_t)(c0 + ty * 4 + j) * DMODEL + r0 + tx;
        _Float16 h, l;
        split_val(v, h, l);
        thi[idx] = h;
        tlo[idx] = l;
    }
}

// ---------------------------------------------------------------------------
// Split-precision fp16 MFMA GEMM (3-product): score path + Q/K projections.
//   C = scale * (Ahi+Alo) @ (Bhi+Blo)^T, both K-major.
// Tile 128x128, BK=32, 256 thr = 4 waves, wave 64x64. 32 KB LDS.
// ---------------------------------------------------------------------------
template <int OUT_SPLIT>
__global__ __launch_bounds__(256) void gemm_mfma(
    const _Float16* __restrict__ Ahi, const _Float16* __restrict__ Alo, int lda,
    const _Float16* __restrict__ Bhi, const _Float16* __restrict__ Blo, int ldb,
    float* __restrict__ Cf, _Float16* __restrict__ Chi, _Float16* __restrict__ Clo,
    int N, int K, float scale) {
    __shared__ _Float16 Ah[128][32];
    __shared__ _Float16 Al[128][32];
    __shared__ _Float16 Bh[128][32];
    __shared__ _Float16 Bl[128][32];

    const int tid = threadIdx.x;
    const int lane = tid & 63;
    const int w = tid >> 6;
    const int wm = (w >> 1) * 64;
    const int wn = (w & 1) * 64;

    const int rowA0 = blockIdx.y * 128;
    const int colB0 = blockIdx.x * 128;

    const int sr = lane >> 2;
    const int sc = lane & 3;
    const int r0 = w * 32 + sr;
    const int r1 = r0 + 16;
    const int cg0 = sc ^ ((r0 >> 1) & 3);
    const int cg1 = sc ^ ((r1 >> 1) & 3);

    const char* gp[8];
    gp[0] = (const char*)(Ahi + (size_t)(rowA0 + r0) * lda) + cg0 * 16;
    gp[1] = (const char*)(Ahi + (size_t)(rowA0 + r1) * lda) + cg1 * 16;
    gp[2] = (const char*)(Alo + (size_t)(rowA0 + r0) * lda) + cg0 * 16;
    gp[3] = (const char*)(Alo + (size_t)(rowA0 + r1) * lda) + cg1 * 16;
    gp[4] = (const char*)(Bhi + (size_t)(colB0 + r0) * ldb) + cg0 * 16;
    gp[5] = (const char*)(Bhi + (size_t)(colB0 + r1) * ldb) + cg1 * 16;
    gp[6] = (const char*)(Blo + (size_t)(colB0 + r0) * ldb) + cg0 * 16;
    gp[7] = (const char*)(Blo + (size_t)(colB0 + r1) * ldb) + cg1 * 16;

    _Float16* lp[8] = {
        &Ah[w * 32][0], &Ah[w * 32 + 16][0],
        &Al[w * 32][0], &Al[w * 32 + 16][0],
        &Bh[w * 32][0], &Bh[w * 32 + 16][0],
        &Bl[w * 32][0], &Bl[w * 32 + 16][0],
    };

    const int fm = lane & 15;
    const int fq = lane >> 4;
    const int ck = ((fq ^ ((fm >> 1) & 3)) * 8);

    floatx4 acc[4][4] = {};

    for (int k0 = 0; k0 < K; k0 += 32) {
#pragma unroll
        for (int t = 0; t < 8; ++t)
            __builtin_amdgcn_global_load_lds(
                (const __attribute__((address_space(1))) void*)gp[t],
                (__attribute__((address_space(3))) void*)lp[t], 16, 0, 0);
#pragma unroll
        for (int t = 0; t < 8; ++t) gp[t] += 64;
        __syncthreads();

        half8 ahv[4], bhv[4], blv[4], alv[4];
#pragma unroll
        for (int i = 0; i < 4; ++i) {
            ahv[i] = *(const half8*)&Ah[wm + i * 16 + fm][ck];
            bhv[i] = *(const half8*)&Bh[wn + i * 16 + fm][ck];
        }
#pragma unroll
        for (int i = 0; i < 4; ++i)
#pragma unroll
            for (int j = 0; j < 4; ++j)
                acc[i][j] = __builtin_amdgcn_mfma_f32_16x16x32_f16(ahv[i], bhv[j], acc[i][j], 0, 0, 0);
#pragma unroll
        for (int i = 0; i < 4; ++i) blv[i] = *(const half8*)&Bl[wn + i * 16 + fm][ck];
#pragma unroll
        for (int i = 0; i < 4; ++i)
#pragma unroll
            for (int j = 0; j < 4; ++j)
                acc[i][j] = __builtin_amdgcn_mfma_f32_16x16x32_f16(ahv[i], blv[j], acc[i][j], 0, 0, 0);
#pragma unroll
        for (int i = 0; i < 4; ++i) alv[i] = *(const half8*)&Al[wm + i * 16 + fm][ck];
#pragma unroll
        for (int i = 0; i < 4; ++i)
#pragma unroll
            for (int j = 0; j < 4; ++j)
                acc[i][j] = __builtin_amdgcn_mfma_f32_16x16x32_f16(alv[i], bhv[j], acc[i][j], 0, 0, 0);
        __syncthreads();
    }

#pragma unroll
    for (int i = 0; i < 4; ++i) {
        const int growb = rowA0 + wm + i * 16 + fq * 4;
#pragma unroll
        for (int j = 0; j < 4; ++j) {
            const int gcol = colB0 + wn + j * 16 + fm;
#pragma unroll
            for (int r = 0; r < 4; ++r) {
                float v = acc[i][j][r] * scale;
                size_t idx = (size_t)(growb + r) * N + gcol;
                if (OUT_SPLIT) {
                    _Float16 h, l;
                    split_val(v, h, l);
                    Chi[idx] = h;
                    Clo[idx] = l;
                } else {
                    Cf[idx] = v;
                }
            }
        }
    }
}

// ---------------------------------------------------------------------------
// Plain fp16 MFMA GEMM (single product): PV and V-projection.
//   C = A @ B^T, A[M][K] fp16 (lda), B[N][K] fp16 (ldb), K-major.
// OUT_HALF==0: fp32 out. OUT_HALF==1: fp16 out.
// Tile 128x128, BK=32, 16 KB LDS, 4 glds : 8 ds_read : 16 MFMA per K-step.
// ---------------------------------------------------------------------------
template <int OUT_HALF>
__global__ __launch_bounds__(256) void gemm_h16(
    const _Float16* __restrict__ A, int lda,
    const _Float16* __restrict__ B, int ldb,
    float* __restrict__ Cf, _Float16* __restrict__ Ch,
    int N, int K) {
    __shared__ _Float16 Ah[128][32];
    __shared__ _Float16 Bh[128][32];

    const int tid = threadIdx.x;
    const int lane = tid & 63;
    const int w = tid >> 6;
    const int wm = (w >> 1) * 64;
    const int wn = (w & 1) * 64;

    const int rowA0 = blockIdx.y * 128;
    const int colB0 = blockIdx.x * 128;

    const int sr = lane >> 2;
    const int sc = lane & 3;
    const int r0 = w * 32 + sr;
    const int r1 = r0 + 16;
    const int cg0 = sc ^ ((r0 >> 1) & 3);
    const int cg1 = sc ^ ((r1 >> 1) & 3);

    const char* gp[4];
    gp[0] = (const char*)(A + (size_t)(rowA0 + r0) * lda) + cg0 * 16;
    gp[1] = (const char*)(A + (size_t)(rowA0 + r1) * lda) + cg1 * 16;
    gp[2] = (const char*)(B + (size_t)(colB0 + r0) * ldb) + cg0 * 16;
    gp[3] = (const char*)(B + (size_t)(colB0 + r1) * ldb) + cg1 * 16;

    _Float16* lp[4] = {
        &Ah[w * 32][0], &Ah[w * 32 + 16][0],
        &Bh[w * 32][0], &Bh[w * 32 + 16][0],
    };

    const int fm = lane & 15;
    const int fq = lane >> 4;
    const int ck = ((fq ^ ((fm >> 1) & 3)) * 8);

    floatx4 acc[4][4] = {};

    for (int k0 = 0; k0 < K; k0 += 32) {
#pragma unroll
        for (int t = 0; t < 4; ++t)
            __builtin_amdgcn_global_load_lds(
                (const __attribute__((address_space(1))) void*)gp[t],
                (__attribute__((address_space(3))) void*)lp[t], 16, 0, 0);
#pragma unroll
        for (int t = 0; t < 4; ++t) gp[t] += 64;
        __syncthreads();

        half8 av[4], bv[4];
#pragma unroll
        for (int i = 0; i < 4; ++i) {
            av[i] = *(const half8*)&Ah[wm + i * 16 + fm][ck];
            bv[i] = *(const half8*)&Bh[wn + i * 16 + fm][ck];
        }
#pragma unroll
        for (int i = 0; i < 4; ++i)
#pragma unroll
            for (int j = 0; j < 4; ++j)
                acc[i][j] = __builtin_amdgcn_mfma_f32_16x16x32_f16(av[i], bv[j], acc[i][j], 0, 0, 0);
        __syncthreads();
    }

#pragma unroll
    for (int i = 0; i < 4; ++i) {
        const int growb = rowA0 + wm + i * 16 + fq * 4;
#pragma unroll
        for (int j = 0; j < 4; ++j) {
            const int gcol = colB0 + wn + j * 16 + fm;
#pragma unroll
            for (int r = 0; r < 4; ++r) {
                float v = acc[i][j][r];
                size_t idx = (size_t)(growb + r) * N + gcol;
                if (OUT_HALF) Ch[idx] = (_Float16)v;
                else          Cf[idx] = v;
            }
        }
    }
}

// ---------------------------------------------------------------------------
// Row softmax over S[SEQ][SEQ] fp32 -> P_hi fp16 written into the row's own
// 16 KB slot (row stride stays 8192 halfs). lo is dropped (error <= 2^-11).
// ---------------------------------------------------------------------------
__global__ __launch_bounds__(256) void softmax_rows_h(float* __restrict__ S) {
    __shared__ float redmax[4];
    __shared__ float redsum[4];
    const int tid = threadIdx.x;
    float* rowp = S + (size_t)blockIdx.x * SEQ;

    float4 v[4];
#pragma unroll
    for (int i = 0; i < 4; ++i)
        v[i] = *(const float4*)(rowp + i * 1024 + (tid << 2));

    float m = -INFINITY;
#pragma unroll
    for (int i = 0; i < 4; ++i)
        m = fmaxf(m, fmaxf(fmaxf(v[i].x, v[i].y), fmaxf(v[i].z, v[i].w)));
#pragma unroll
    for (int off = 32; off > 0; off >>= 1) m = fmaxf(m, __shfl_xor(m, off));
    if ((tid & 63) == 0) redmax[tid >> 6] = m;
    __syncthreads();   // all loads complete before any write below
    m = fmaxf(fmaxf(redmax[0], redmax[1]), fmaxf(redmax[2], redmax[3]));

    float s = 0.f;
#pragma unroll
    for (int i = 0; i < 4; ++i) {
        v[i].x = expf(v[i].x - m); s += v[i].x;
        v[i].y = expf(v[i].y - m); s += v[i].y;
        v[i].z = expf(v[i].z - m); s += v[i].z;
        v[i].w = expf(v[i].w - m); s += v[i].w;
    }
#pragma unroll
    for (int off = 32; off > 0; off >>= 1) s += __shfl_xor(s, off);
    if ((tid & 63) == 0) redsum[tid >> 6] = s;
    __syncthreads();
    s = redsum[0] + redsum[1] + redsum[2] + redsum[3];

    const float inv = 1.0f / s;
    _Float16* hp = (_Float16*)rowp;
#pragma unroll
    for (int i = 0; i < 4; ++i) {
        half4v h;
        h[0] = (_Float16)(v[i].x * inv);
        h[1] = (_Float16)(v[i].y * inv);
        h[2] = (_Float16)(v[i].z * inv);
        h[3] = (_Float16)(v[i].w * inv);
        *(half4v*)(hp + i * 1024 + (tid << 2)) = h;
    }
}

// ---------------------------------------------------------------------------
// Workspace layout (104 MB used):
//  [0,64M)   S fp32 4096x4096; after softmax row i holds P_hi in its first
//            8 KB (A-stride 8192 halfs). Early (dead before S): x_hi/x_lo/wT.
//  [64,72M)  Q_hi  [72,80M) Q_lo  [80,88M) K_hi  [88,96M) K_lo
//  [96,104M) VT fp16 [1024][4096]  (plain, no split)
// ---------------------------------------------------------------------------
extern "C" void kernel_launch(void* const* d_in, const int* in_sizes, int n_in,
                              void* d_out, int out_size, void* d_ws, size_t ws_size,
                              hipStream_t stream) {
    const float* x  = (const float*)d_in[0];
    const float* wq = (const float*)d_in[1];
    const float* wk = (const float*)d_in[2];
    const float* wv = (const float*)d_in[3];
    float* out = (float*)d_out;

    char* base = (char*)d_ws;
    const size_t MB = 1u << 20;
    float*    S      = (float*)base;
    _Float16* x_hi   = (_Float16*)(base + 0 * MB);
    _Float16* x_lo   = (_Float16*)(base + 8 * MB);
    _Float16* wqT_hi = (_Float16*)(base + 16 * MB);
    _Float16* wqT_lo = (_Float16*)(base + 18 * MB);
    _Float16* wkT_hi = (_Float16*)(base + 20 * MB);
    _Float16* wkT_lo = (_Float16*)(base + 22 * MB);
    _Float16* wvT_hi = (_Float16*)(base + 24 * MB);
    _Float16* wvT_lo = (_Float16*)(base + 26 * MB);
    _Float16* Q_hi   = (_Float16*)(base + 64 * MB);
    _Float16* Q_lo   = (_Float16*)(base + 72 * MB);
    _Float16* K_hi   = (_Float16*)(base + 80 * MB);
    _Float16* K_lo   = (_Float16*)(base + 88 * MB);
    _Float16* VT     = (_Float16*)(base + 96 * MB);

    // 1) splits
    split_f32<<<4096, 256, 0, stream>>>(x, x_hi, x_lo, SEQ * DMODEL / 4);
    dim3 tg(32, 32);
    transpose_split<<<tg, 256, 0, stream>>>(wq, wqT_hi, wqT_lo);
    transpose_split<<<tg, 256, 0, stream>>>(wk, wkT_hi, wkT_lo);
    transpose_split<<<tg, 256, 0, stream>>>(wv, wvT_hi, wvT_lo);

    // 2) projections
    dim3 gqk(DMODEL / 128, SEQ / 128);   // (8,32)
    gemm_mfma<1><<<gqk, 256, 0, stream>>>(x_hi, x_lo, DMODEL, wqT_hi, wqT_lo, DMODEL,
                                          nullptr, Q_hi, Q_lo, DMODEL, DMODEL, 1.0f);
    gemm_mfma<1><<<gqk, 256, 0, stream>>>(x_hi, x_lo, DMODEL, wkT_hi, wkT_lo, DMODEL,
                                          nullptr, K_hi, K_lo, DMODEL, DMODEL, 1.0f);
    // V^T = wv^T @ x^T, plain fp16 single-product (tolerant consumer)
    dim3 gvt(SEQ / 128, DMODEL / 128);   // (32,8)
    gemm_h16<1><<<gvt, 256, 0, stream>>>(wvT_hi, DMODEL, x_hi, DMODEL,
                                         nullptr, VT, SEQ, DMODEL);

    // 3) scores: S = (Q @ K^T) / 32  (full 3-product split precision)
    dim3 gs(SEQ / 128, SEQ / 128);       // (32,32)
    gemm_mfma<0><<<gs, 256, 0, stream>>>(Q_hi, Q_lo, DMODEL, K_hi, K_lo, DMODEL,
                                         S, nullptr, nullptr, SEQ, DMODEL, 1.0f / 32.0f);

    // 4) softmax -> P_hi fp16 (in place, row stride 8192 halfs)
    softmax_rows_h<<<SEQ, 256, 0, stream>>>(S);

    // 5) out = P @ V, plain fp16 single-product
    dim3 go(DMODEL / 128, SEQ / 128);    // (8,32)
    gemm_h16<0><<<go, 256, 0, stream>>>((_Float16*)S, 2 * SEQ, VT, SEQ,
                                        out, nullptr, DMODEL, SEQ);
}

// Round 6
// 375.798 us; speedup vs baseline: 3.4759x; 1.1740x over previous
//
#include <hip/hip_runtime.h>
#include <hip/hip_fp16.h>
#include <math.h>

#define SEQ    4096
#define DMODEL 1024

typedef _Float16 half8  __attribute__((ext_vector_type(8)));
typedef _Float16 half4v __attribute__((ext_vector_type(4)));
typedef float    floatx4 __attribute__((ext_vector_type(4)));

__device__ inline void split_val(float v, _Float16& h, _Float16& l) {
    _Float16 hh = (_Float16)v;
    h = hh;
    l = (_Float16)(v - (float)hh);
}

// ---------------------------------------------------------------------------
// Elementwise split: in[n] fp32 -> hi[n], lo[n] fp16
// ---------------------------------------------------------------------------
__global__ __launch_bounds__(256) void split_f32(const float* __restrict__ in,
                                                 _Float16* __restrict__ hi,
                                                 _Float16* __restrict__ lo, int n4) {
    int i = blockIdx.x * 256 + threadIdx.x;
    for (; i < n4; i += gridDim.x * 256) {
        floatx4 v = *(const floatx4*)(in + 4 * (size_t)i);
        half4v h, l;
#pragma unroll
        for (int j = 0; j < 4; ++j) {
            _Float16 hh = (_Float16)v[j];
            _Float16 ll = (_Float16)(v[j] - (float)hh);
            h[j] = hh;
            l[j] = ll;
        }
        *(half4v*)(hi + 4 * (size_t)i) = h;
        *(half4v*)(lo + 4 * (size_t)i) = l;
    }
}

// ---------------------------------------------------------------------------
// Transpose + split: w[1024][1024] fp32 -> thi/tlo = w^T (fp16 hi/lo planes)
// ---------------------------------------------------------------------------
__global__ __launch_bounds__(256) void transpose_split(const float* __restrict__ w,
                                                       _Float16* __restrict__ thi,
                                                       _Float16* __restrict__ tlo) {
    __shared__ float tile[32][33];
    const int tx = threadIdx.x & 31, ty = threadIdx.x >> 5;
    const int c0 = blockIdx.x * 32, r0 = blockIdx.y * 32;
#pragma unroll
    for (int j = 0; j < 4; ++j)
        tile[ty * 4 + j][tx] = w[(size_t)(r0 + ty * 4 + j) * DMODEL + c0 + tx];
    __syncthreads();
#pragma unroll
    for (int j = 0; j < 4; ++j) {
        float v = tile[tx][ty * 4 + j];
        size_t idx = (size_t)(c0 + ty * 4 + j) * DMODEL + r0 + tx;
        _Float16 h, l;
        split_val(v, h, l);
        thi[idx] = h;
        tlo[idx] = l;
    }
}

// Plain fp16 transpose (no lo plane) — for wv.
__global__ __launch_bounds__(256) void transpose_h(const float* __restrict__ w,
                                                   _Float16* __restrict__ th) {
    __shared__ float tile[32][33];
    const int tx = threadIdx.x & 31, ty = threadIdx.x >> 5;
    const int c0 = blockIdx.x * 32, r0 = blockIdx.y * 32;
#pragma unroll
    for (int j = 0; j < 4; ++j)
        tile[ty * 4 + j][tx] = w[(size_t)(r0 + ty * 4 + j) * DMODEL + c0 + tx];
    __syncthreads();
#pragma unroll
    for (int j = 0; j < 4; ++j)
        th[(size_t)(c0 + ty * 4 + j) * DMODEL + r0 + tx] =
            (_Float16)tile[tx][ty * 4 + j];
}

// ---------------------------------------------------------------------------
// Split-precision fp16 MFMA GEMM (3-product): score path + fused QK proj.
//   C = scale * (Ahi+Alo) @ (Bhi+Blo)^T, both K-major.
// Tile 128x128, BK=32, 256 thr = 4 waves, wave 64x64. 32 KB LDS.
// ---------------------------------------------------------------------------
template <int OUT_SPLIT>
__global__ __launch_bounds__(256) void gemm_mfma(
    const _Float16* __restrict__ Ahi, const _Float16* __restrict__ Alo, int lda,
    const _Float16* __restrict__ Bhi, const _Float16* __restrict__ Blo, int ldb,
    float* __restrict__ Cf, _Float16* __restrict__ Chi, _Float16* __restrict__ Clo,
    int N, int K, float scale) {
    __shared__ _Float16 Ah[128][32];
    __shared__ _Float16 Al[128][32];
    __shared__ _Float16 Bh[128][32];
    __shared__ _Float16 Bl[128][32];

    const int tid = threadIdx.x;
    const int lane = tid & 63;
    const int w = tid >> 6;
    const int wm = (w >> 1) * 64;
    const int wn = (w & 1) * 64;

    const int rowA0 = blockIdx.y * 128;
    const int colB0 = blockIdx.x * 128;

    const int sr = lane >> 2;
    const int sc = lane & 3;
    const int r0 = w * 32 + sr;
    const int r1 = r0 + 16;
    const int cg0 = sc ^ ((r0 >> 1) & 3);
    const int cg1 = sc ^ ((r1 >> 1) & 3);

    const char* gp[8];
    gp[0] = (const char*)(Ahi + (size_t)(rowA0 + r0) * lda) + cg0 * 16;
    gp[1] = (const char*)(Ahi + (size_t)(rowA0 + r1) * lda) + cg1 * 16;
    gp[2] = (const char*)(Alo + (size_t)(rowA0 + r0) * lda) + cg0 * 16;
    gp[3] = (const char*)(Alo + (size_t)(rowA0 + r1) * lda) + cg1 * 16;
    gp[4] = (const char*)(Bhi + (size_t)(colB0 + r0) * ldb) + cg0 * 16;
    gp[5] = (const char*)(Bhi + (size_t)(colB0 + r1) * ldb) + cg1 * 16;
    gp[6] = (const char*)(Blo + (size_t)(colB0 + r0) * ldb) + cg0 * 16;
    gp[7] = (const char*)(Blo + (size_t)(colB0 + r1) * ldb) + cg1 * 16;

    _Float16* lp[8] = {
        &Ah[w * 32][0], &Ah[w * 32 + 16][0],
        &Al[w * 32][0], &Al[w * 32 + 16][0],
        &Bh[w * 32][0], &Bh[w * 32 + 16][0],
        &Bl[w * 32][0], &Bl[w * 32 + 16][0],
    };

    const int fm = lane & 15;
    const int fq = lane >> 4;
    const int ck = ((fq ^ ((fm >> 1) & 3)) * 8);

    floatx4 acc[4][4] = {};

    for (int k0 = 0; k0 < K; k0 += 32) {
#pragma unroll
        for (int t = 0; t < 8; ++t)
            __builtin_amdgcn_global_load_lds(
                (const __attribute__((address_space(1))) void*)gp[t],
                (__attribute__((address_space(3))) void*)lp[t], 16, 0, 0);
#pragma unroll
        for (int t = 0; t < 8; ++t) gp[t] += 64;
        __syncthreads();

        half8 ahv[4], bhv[4], blv[4], alv[4];
#pragma unroll
        for (int i = 0; i < 4; ++i) {
            ahv[i] = *(const half8*)&Ah[wm + i * 16 + fm][ck];
            bhv[i] = *(const half8*)&Bh[wn + i * 16 + fm][ck];
        }
#pragma unroll
        for (int i = 0; i < 4; ++i)
#pragma unroll
            for (int j = 0; j < 4; ++j)
                acc[i][j] = __builtin_amdgcn_mfma_f32_16x16x32_f16(ahv[i], bhv[j], acc[i][j], 0, 0, 0);
#pragma unroll
        for (int i = 0; i < 4; ++i) blv[i] = *(const half8*)&Bl[wn + i * 16 + fm][ck];
#pragma unroll
        for (int i = 0; i < 4; ++i)
#pragma unroll
            for (int j = 0; j < 4; ++j)
                acc[i][j] = __builtin_amdgcn_mfma_f32_16x16x32_f16(ahv[i], blv[j], acc[i][j], 0, 0, 0);
#pragma unroll
        for (int i = 0; i < 4; ++i) alv[i] = *(const half8*)&Al[wm + i * 16 + fm][ck];
#pragma unroll
        for (int i = 0; i < 4; ++i)
#pragma unroll
            for (int j = 0; j < 4; ++j)
                acc[i][j] = __builtin_amdgcn_mfma_f32_16x16x32_f16(alv[i], bhv[j], acc[i][j], 0, 0, 0);
        __syncthreads();
    }

#pragma unroll
    for (int i = 0; i < 4; ++i) {
        const int growb = rowA0 + wm + i * 16 + fq * 4;
#pragma unroll
        for (int j = 0; j < 4; ++j) {
            const int gcol = colB0 + wn + j * 16 + fm;
#pragma unroll
            for (int r = 0; r < 4; ++r) {
                float v = acc[i][j][r] * scale;
                size_t idx = (size_t)(growb + r) * N + gcol;
                if (OUT_SPLIT) {
                    _Float16 h, l;
                    split_val(v, h, l);
                    Chi[idx] = h;
                    Clo[idx] = l;
                } else {
                    Cf[idx] = v;
                }
            }
        }
    }
}

// ---------------------------------------------------------------------------
// Plain fp16 MFMA GEMM, tile 128x64 (more blocks for small-N problems):
//   C = A @ B^T, A[M][K] (lda), B[N][K] (ldb), K-major. PV + V-projection.
// 256 thr = 4 waves (2x2), wave tile 64x32, acc 4x2. 12 KB LDS.
// ---------------------------------------------------------------------------
template <int OUT_HALF>
__global__ __launch_bounds__(256) void gemm_h16_n64(
    const _Float16* __restrict__ A, int lda,
    const _Float16* __restrict__ B, int ldb,
    float* __restrict__ Cf, _Float16* __restrict__ Ch,
    int N, int K) {
    __shared__ _Float16 Ah[128][32];
    __shared__ _Float16 Bh[64][32];

    const int tid = threadIdx.x;
    const int lane = tid & 63;
    const int w = tid >> 6;
    const int wm = (w >> 1) * 64;     // wave row offset (2 row-groups)
    const int wn = (w & 1) * 32;      // wave col offset (2 col-groups)

    const int rowA0 = blockIdx.y * 128;
    const int colB0 = blockIdx.x * 64;

    const int sr = lane >> 2;
    const int sc = lane & 3;
    // A: rows w*32+sr, w*32+16+sr (covers 128 across 4 waves, 2 glds each)
    const int ra0 = w * 32 + sr;
    const int ra1 = ra0 + 16;
    // B: rows w*16+sr (covers 64 across 4 waves, 1 glds each)
    const int rb0 = w * 16 + sr;
    const int cga0 = sc ^ ((ra0 >> 1) & 3);
    const int cga1 = sc ^ ((ra1 >> 1) & 3);
    const int cgb0 = sc ^ ((rb0 >> 1) & 3);

    const char* gp[3];
    gp[0] = (const char*)(A + (size_t)(rowA0 + ra0) * lda) + cga0 * 16;
    gp[1] = (const char*)(A + (size_t)(rowA0 + ra1) * lda) + cga1 * 16;
    gp[2] = (const char*)(B + (size_t)(colB0 + rb0) * ldb) + cgb0 * 16;

    _Float16* lp[3] = {
        &Ah[w * 32][0], &Ah[w * 32 + 16][0],
        &Bh[w * 16][0],
    };

    const int fm = lane & 15;
    const int fq = lane >> 4;
    const int ck = ((fq ^ ((fm >> 1) & 3)) * 8);

    floatx4 acc[4][2] = {};

    for (int k0 = 0; k0 < K; k0 += 32) {
#pragma unroll
        for (int t = 0; t < 3; ++t)
            __builtin_amdgcn_global_load_lds(
                (const __attribute__((address_space(1))) void*)gp[t],
                (__attribute__((address_space(3))) void*)lp[t], 16, 0, 0);
#pragma unroll
        for (int t = 0; t < 3; ++t) gp[t] += 64;
        __syncthreads();

        half8 av[4], bv[2];
#pragma unroll
        for (int i = 0; i < 4; ++i)
            av[i] = *(const half8*)&Ah[wm + i * 16 + fm][ck];
#pragma unroll
        for (int j = 0; j < 2; ++j)
            bv[j] = *(const half8*)&Bh[wn + j * 16 + fm][ck];
#pragma unroll
        for (int i = 0; i < 4; ++i)
#pragma unroll
            for (int j = 0; j < 2; ++j)
                acc[i][j] = __builtin_amdgcn_mfma_f32_16x16x32_f16(av[i], bv[j], acc[i][j], 0, 0, 0);
        __syncthreads();
    }

#pragma unroll
    for (int i = 0; i < 4; ++i) {
        const int growb = rowA0 + wm + i * 16 + fq * 4;
#pragma unroll
        for (int j = 0; j < 2; ++j) {
            const int gcol = colB0 + wn + j * 16 + fm;
#pragma unroll
            for (int r = 0; r < 4; ++r) {
                float v = acc[i][j][r];
                size_t idx = (size_t)(growb + r) * N + gcol;
                if (OUT_HALF) Ch[idx] = (_Float16)v;
                else          Cf[idx] = v;
            }
        }
    }
}

// ---------------------------------------------------------------------------
// Row softmax over S[SEQ][SEQ] fp32 -> P_hi fp16 in the row's first 8 KB
// (A-stride stays 8192 halfs).
// ---------------------------------------------------------------------------
__global__ __launch_bounds__(256) void softmax_rows_h(float* __restrict__ S) {
    __shared__ float redmax[4];
    __shared__ float redsum[4];
    const int tid = threadIdx.x;
    float* rowp = S + (size_t)blockIdx.x * SEQ;

    float4 v[4];
#pragma unroll
    for (int i = 0; i < 4; ++i)
        v[i] = *(const float4*)(rowp + i * 1024 + (tid << 2));

    float m = -INFINITY;
#pragma unroll
    for (int i = 0; i < 4; ++i)
        m = fmaxf(m, fmaxf(fmaxf(v[i].x, v[i].y), fmaxf(v[i].z, v[i].w)));
#pragma unroll
    for (int off = 32; off > 0; off >>= 1) m = fmaxf(m, __shfl_xor(m, off));
    if ((tid & 63) == 0) redmax[tid >> 6] = m;
    __syncthreads();
    m = fmaxf(fmaxf(redmax[0], redmax[1]), fmaxf(redmax[2], redmax[3]));

    float s = 0.f;
#pragma unroll
    for (int i = 0; i < 4; ++i) {
        v[i].x = expf(v[i].x - m); s += v[i].x;
        v[i].y = expf(v[i].y - m); s += v[i].y;
        v[i].z = expf(v[i].z - m); s += v[i].z;
        v[i].w = expf(v[i].w - m); s += v[i].w;
    }
#pragma unroll
    for (int off = 32; off > 0; off >>= 1) s += __shfl_xor(s, off);
    if ((tid & 63) == 0) redsum[tid >> 6] = s;
    __syncthreads();
    s = redsum[0] + redsum[1] + redsum[2] + redsum[3];

    const float inv = 1.0f / s;
    _Float16* hp = (_Float16*)rowp;
#pragma unroll
    for (int i = 0; i < 4; ++i) {
        half4v h;
        h[0] = (_Float16)(v[i].x * inv);
        h[1] = (_Float16)(v[i].y * inv);
        h[2] = (_Float16)(v[i].z * inv);
        h[3] = (_Float16)(v[i].w * inv);
        *(half4v*)(hp + i * 1024 + (tid << 2)) = h;
    }
}

// ---------------------------------------------------------------------------
// Workspace layout (112 MB used):
//  [0,64M)   S fp32 4096x4096; after softmax row i holds P_hi in first 8 KB.
//            Early (dead before S written): x_hi [0,8M), x_lo [8,16M),
//            wqkT_hi [16,20M), wqkT_lo [20,24M), wvT [24,26M)
//  [64,80M)  QK_hi fp16 [4096][2048]  (Q = cols 0..1023, K = cols 1024..2047)
//  [80,96M)  QK_lo fp16 [4096][2048]
//  [96,104M) VT fp16 [1024][4096]
// ---------------------------------------------------------------------------
extern "C" void kernel_launch(void* const* d_in, const int* in_sizes, int n_in,
                              void* d_out, int out_size, void* d_ws, size_t ws_size,
                              hipStream_t stream) {
    const float* x  = (const float*)d_in[0];
    const float* wq = (const float*)d_in[1];
    const float* wk = (const float*)d_in[2];
    const float* wv = (const float*)d_in[3];
    float* out = (float*)d_out;

    char* base = (char*)d_ws;
    const size_t MB = 1u << 20;
    float*    S       = (float*)base;
    _Float16* x_hi    = (_Float16*)(base + 0 * MB);
    _Float16* x_lo    = (_Float16*)(base + 8 * MB);
    _Float16* wqkT_hi = (_Float16*)(base + 16 * MB);   // [2048][1024]
    _Float16* wqkT_lo = (_Float16*)(base + 20 * MB);
    _Float16* wvT     = (_Float16*)(base + 24 * MB);   // [1024][1024]
    _Float16* QK_hi   = (_Float16*)(base + 64 * MB);   // [4096][2048]
    _Float16* QK_lo   = (_Float16*)(base + 80 * MB);
    _Float16* VT      = (_Float16*)(base + 96 * MB);   // [1024][4096]

    // 1) splits / transposes
    split_f32<<<4096, 256, 0, stream>>>(x, x_hi, x_lo, SEQ * DMODEL / 4);
    dim3 tg(32, 32);
    transpose_split<<<tg, 256, 0, stream>>>(wq, wqkT_hi, wqkT_lo);
    transpose_split<<<tg, 256, 0, stream>>>(wk, wqkT_hi + 1024 * 1024, wqkT_lo + 1024 * 1024);
    transpose_h<<<tg, 256, 0, stream>>>(wv, wvT);

    // 2) fused Q+K projection: [4096,1024] @ [1024,2048-combined] -> QK (split)
    dim3 gqk(2048 / 128, SEQ / 128);   // (16,32) = 512 blocks
    gemm_mfma<1><<<gqk, 256, 0, stream>>>(x_hi, x_lo, DMODEL, wqkT_hi, wqkT_lo, DMODEL,
                                          nullptr, QK_hi, QK_lo, 2048, DMODEL, 1.0f);
    // V^T = wv^T @ x^T, plain fp16 (tolerant consumer), tile 128x64
    dim3 gvt(SEQ / 64, DMODEL / 128);  // (64,8) = 512 blocks
    gemm_h16_n64<1><<<gvt, 256, 0, stream>>>(wvT, DMODEL, x_hi, DMODEL,
                                             nullptr, VT, SEQ, DMODEL);

    // 3) scores: S = (Q @ K^T) / 32  (3-product split precision)
    dim3 gs(SEQ / 128, SEQ / 128);     // (32,32) = 1024 blocks
    gemm_mfma<0><<<gs, 256, 0, stream>>>(QK_hi, QK_lo, 2048,
                                         QK_hi + 1024, QK_lo + 1024, 2048,
                                         S, nullptr, nullptr, SEQ, DMODEL, 1.0f / 32.0f);

    // 4) softmax -> P_hi fp16 (in place)
    softmax_rows_h<<<SEQ, 256, 0, stream>>>(S);

    // 5) out = P @ V, plain fp16, tile 128x64
    dim3 go(DMODEL / 64, SEQ / 128);   // (16,32) = 512 blocks
    gemm_h16_n64<0><<<go, 256, 0, stream>>>((_Float16*)S, 2 * SEQ, VT, SEQ,
                                            out, nullptr, DMODEL, SEQ);
}

// Round 8
// 370.399 us; speedup vs baseline: 3.5265x; 1.0146x over previous
//
#include <hip/hip_runtime.h>
#include <hip/hip_fp16.h>
#include <math.h>

#define SEQ    4096
#define DMODEL 1024

typedef _Float16 half8  __attribute__((ext_vector_type(8)));
typedef _Float16 half4v __attribute__((ext_vector_type(4)));
typedef float    floatx4 __attribute__((ext_vector_type(4)));

__device__ inline void split_val(float v, _Float16& h, _Float16& l) {
    _Float16 hh = (_Float16)v;
    h = hh;
    l = (_Float16)(v - (float)hh);
}

// ---------------------------------------------------------------------------
// Fused prep: blocks 0..3071 transpose wq/wk/wv (32x32 tiles); blocks
// 3072..4095 split x into hi/lo fp16 — each split thread handles FOUR float4s
// (1024 blocks x 256 thr x 4 float4 = 1,048,576 float4 = all of x).
// All branches block-uniform.
// ---------------------------------------------------------------------------
__global__ __launch_bounds__(256) void prep(const float* __restrict__ x,
                                            const float* __restrict__ wq,
                                            const float* __restrict__ wk,
                                            const float* __restrict__ wv,
                                            _Float16* __restrict__ x_hi,
                                            _Float16* __restrict__ x_lo,
                                            _Float16* __restrict__ wqkT_hi,
                                            _Float16* __restrict__ wqkT_lo,
                                            _Float16* __restrict__ wvT) {
    __shared__ float tile[32][33];
    const int b = blockIdx.x;
    if (b < 3072) {
        const int which = b >> 10;           // 0=wq 1=wk 2=wv
        const int bb = b & 1023;
        const int c0 = (bb & 31) * 32;       // col tile in w
        const int r0 = (bb >> 5) * 32;       // row tile in w
        const float* w = (which == 0) ? wq : (which == 1) ? wk : wv;
        const int tx = threadIdx.x & 31, ty = threadIdx.x >> 5;
#pragma unroll
        for (int j = 0; j < 4; ++j)
            tile[ty * 4 + j][tx] = w[(size_t)(r0 + ty * 4 + j) * DMODEL + c0 + tx];
        __syncthreads();
        if (which < 2) {
            _Float16* th = wqkT_hi + (size_t)which * DMODEL * DMODEL;
            _Float16* tl = wqkT_lo + (size_t)which * DMODEL * DMODEL;
#pragma unroll
            for (int j = 0; j < 4; ++j) {
                float v = tile[tx][ty * 4 + j];
                size_t idx = (size_t)(c0 + ty * 4 + j) * DMODEL + r0 + tx;
                _Float16 h, l;
                split_val(v, h, l);
                th[idx] = h;
                tl[idx] = l;
            }
        } else {
#pragma unroll
            for (int j = 0; j < 4; ++j)
                wvT[(size_t)(c0 + ty * 4 + j) * DMODEL + r0 + tx] =
                    (_Float16)tile[tx][ty * 4 + j];
        }
    } else {
        // split x: 1024 blocks, 4 float4 per thread -> full 4096x1024
        const int t0 = (b - 3072) * 256 + threadIdx.x;   // 0..262143
#pragma unroll
        for (int rep = 0; rep < 4; ++rep) {
            const size_t i = (size_t)t0 + (size_t)rep * 262144;
            floatx4 v = *(const floatx4*)(x + 4 * i);
            half4v h, l;
#pragma unroll
            for (int j = 0; j < 4; ++j) {
                _Float16 hh = (_Float16)v[j];
                _Float16 ll = (_Float16)(v[j] - (float)hh);
                h[j] = hh;
                l[j] = ll;
            }
            *(half4v*)(x_hi + 4 * i) = h;
            *(half4v*)(x_lo + 4 * i) = l;
        }
    }
}

// ---------------------------------------------------------------------------
// Split-precision fp16 MFMA GEMM (3-product): score path + fused QK proj.
//   C = scale * (Ahi+Alo) @ (Bhi+Blo)^T, both K-major.
// Tile 128x128, BK=32, 256 thr = 4 waves, wave 64x64. 32 KB LDS.
// OUT_SPLIT==1: columns <1024 -> Chi/Clo, >=1024 -> Chi2/Clo2 (ldc=1024).
// ---------------------------------------------------------------------------
template <int OUT_SPLIT>
__global__ __launch_bounds__(256) void gemm_mfma(
    const _Float16* __restrict__ Ahi, const _Float16* __restrict__ Alo, int lda,
    const _Float16* __restrict__ Bhi, const _Float16* __restrict__ Blo, int ldb,
    float* __restrict__ Cf,
    _Float16* __restrict__ Chi, _Float16* __restrict__ Clo,
    _Float16* __restrict__ Chi2, _Float16* __restrict__ Clo2,
    int N, int K, float scale) {
    __shared__ _Float16 Ah[128][32];
    __shared__ _Float16 Al[128][32];
    __shared__ _Float16 Bh[128][32];
    __shared__ _Float16 Bl[128][32];

    const int tid = threadIdx.x;
    const int lane = tid & 63;
    const int w = tid >> 6;
    const int wm = (w >> 1) * 64;
    const int wn = (w & 1) * 64;

    const int rowA0 = blockIdx.y * 128;
    const int colB0 = blockIdx.x * 128;

    const int sr = lane >> 2;
    const int sc = lane & 3;
    const int r0 = w * 32 + sr;
    const int r1 = r0 + 16;
    const int cg0 = sc ^ ((r0 >> 1) & 3);
    const int cg1 = sc ^ ((r1 >> 1) & 3);

    const char* gp[8];
    gp[0] = (const char*)(Ahi + (size_t)(rowA0 + r0) * lda) + cg0 * 16;
    gp[1] = (const char*)(Ahi + (size_t)(rowA0 + r1) * lda) + cg1 * 16;
    gp[2] = (const char*)(Alo + (size_t)(rowA0 + r0) * lda) + cg0 * 16;
    gp[3] = (const char*)(Alo + (size_t)(rowA0 + r1) * lda) + cg1 * 16;
    gp[4] = (const char*)(Bhi + (size_t)(colB0 + r0) * ldb) + cg0 * 16;
    gp[5] = (const char*)(Bhi + (size_t)(colB0 + r1) * ldb) + cg1 * 16;
    gp[6] = (const char*)(Blo + (size_t)(colB0 + r0) * ldb) + cg0 * 16;
    gp[7] = (const char*)(Blo + (size_t)(colB0 + r1) * ldb) + cg1 * 16;

    _Float16* lp[8] = {
        &Ah[w * 32][0], &Ah[w * 32 + 16][0],
        &Al[w * 32][0], &Al[w * 32 + 16][0],
        &Bh[w * 32][0], &Bh[w * 32 + 16][0],
        &Bl[w * 32][0], &Bl[w * 32 + 16][0],
    };

    const int fm = lane & 15;
    const int fq = lane >> 4;
    const int ck = ((fq ^ ((fm >> 1) & 3)) * 8);

    floatx4 acc[4][4] = {};

    for (int k0 = 0; k0 < K; k0 += 32) {
#pragma unroll
        for (int t = 0; t < 8; ++t)
            __builtin_amdgcn_global_load_lds(
                (const __attribute__((address_space(1))) void*)gp[t],
                (__attribute__((address_space(3))) void*)lp[t], 16, 0, 0);
#pragma unroll
        for (int t = 0; t < 8; ++t) gp[t] += 64;
        __syncthreads();

        half8 ahv[4], bhv[4], blv[4], alv[4];
#pragma unroll
        for (int i = 0; i < 4; ++i) {
            ahv[i] = *(const half8*)&Ah[wm + i * 16 + fm][ck];
            bhv[i] = *(const half8*)&Bh[wn + i * 16 + fm][ck];
        }
#pragma unroll
        for (int i = 0; i < 4; ++i)
#pragma unroll
            for (int j = 0; j < 4; ++j)
                acc[i][j] = __builtin_amdgcn_mfma_f32_16x16x32_f16(ahv[i], bhv[j], acc[i][j], 0, 0, 0);
#pragma unroll
        for (int i = 0; i < 4; ++i) blv[i] = *(const half8*)&Bl[wn + i * 16 + fm][ck];
#pragma unroll
        for (int i = 0; i < 4; ++i)
#pragma unroll
            for (int j = 0; j < 4; ++j)
                acc[i][j] = __builtin_amdgcn_mfma_f32_16x16x32_f16(ahv[i], blv[j], acc[i][j], 0, 0, 0);
#pragma unroll
        for (int i = 0; i < 4; ++i) alv[i] = *(const half8*)&Al[wm + i * 16 + fm][ck];
#pragma unroll
        for (int i = 0; i < 4; ++i)
#pragma unroll
            for (int j = 0; j < 4; ++j)
                acc[i][j] = __builtin_amdgcn_mfma_f32_16x16x32_f16(alv[i], bhv[j], acc[i][j], 0, 0, 0);
        __syncthreads();
    }

    // Epilogue. For OUT_SPLIT: route by column half (block-uniform: a 128-wide
    // tile never straddles col 1024), write at ldc=1024.
    _Float16* dh = Chi;
    _Float16* dl = Clo;
    int cbase = colB0;
    if (OUT_SPLIT && colB0 >= 1024) { dh = Chi2; dl = Clo2; cbase = colB0 - 1024; }

#pragma unroll
    for (int i = 0; i < 4; ++i) {
        const int growb = rowA0 + wm + i * 16 + fq * 4;
#pragma unroll
        for (int j = 0; j < 4; ++j) {
            const int gcol = wn + j * 16 + fm;
#pragma unroll
            for (int r = 0; r < 4; ++r) {
                float v = acc[i][j][r] * scale;
                if (OUT_SPLIT) {
                    size_t idx = (size_t)(growb + r) * 1024 + cbase + gcol;
                    _Float16 h, l;
                    split_val(v, h, l);
                    dh[idx] = h;
                    dl[idx] = l;
                } else {
                    size_t idx = (size_t)(growb + r) * N + colB0 + gcol;
                    Cf[idx] = v;
                }
            }
        }
    }
}

// ---------------------------------------------------------------------------
// Plain fp16 MFMA GEMM, tile 128x64: PV + V-projection.
//   C = A @ B^T, A[M][K] (lda), B[N][K] (ldb), K-major.
// 256 thr = 4 waves (2x2), wave tile 64x32, acc 4x2. 12 KB LDS.
// ---------------------------------------------------------------------------
template <int OUT_HALF>
__global__ __launch_bounds__(256) void gemm_h16_n64(
    const _Float16* __restrict__ A, int lda,
    const _Float16* __restrict__ B, int ldb,
    float* __restrict__ Cf, _Float16* __restrict__ Ch,
    int N, int K) {
    __shared__ _Float16 Ah[128][32];
    __shared__ _Float16 Bh[64][32];

    const int tid = threadIdx.x;
    const int lane = tid & 63;
    const int w = tid >> 6;
    const int wm = (w >> 1) * 64;
    const int wn = (w & 1) * 32;

    const int rowA0 = blockIdx.y * 128;
    const int colB0 = blockIdx.x * 64;

    const int sr = lane >> 2;
    const int sc = lane & 3;
    const int ra0 = w * 32 + sr;
    const int ra1 = ra0 + 16;
    const int rb0 = w * 16 + sr;
    const int cga0 = sc ^ ((ra0 >> 1) & 3);
    const int cga1 = sc ^ ((ra1 >> 1) & 3);
    const int cgb0 = sc ^ ((rb0 >> 1) & 3);

    const char* gp[3];
    gp[0] = (const char*)(A + (size_t)(rowA0 + ra0) * lda) + cga0 * 16;
    gp[1] = (const char*)(A + (size_t)(rowA0 + ra1) * lda) + cga1 * 16;
    gp[2] = (const char*)(B + (size_t)(colB0 + rb0) * ldb) + cgb0 * 16;

    _Float16* lp[3] = {
        &Ah[w * 32][0], &Ah[w * 32 + 16][0],
        &Bh[w * 16][0],
    };

    const int fm = lane & 15;
    const int fq = lane >> 4;
    const int ck = ((fq ^ ((fm >> 1) & 3)) * 8);

    floatx4 acc[4][2] = {};

    for (int k0 = 0; k0 < K; k0 += 32) {
#pragma unroll
        for (int t = 0; t < 3; ++t)
            __builtin_amdgcn_global_load_lds(
                (const __attribute__((address_space(1))) void*)gp[t],
                (__attribute__((address_space(3))) void*)lp[t], 16, 0, 0);
#pragma unroll
        for (int t = 0; t < 3; ++t) gp[t] += 64;
        __syncthreads();

        half8 av[4], bv[2];
#pragma unroll
        for (int i = 0; i < 4; ++i)
            av[i] = *(const half8*)&Ah[wm + i * 16 + fm][ck];
#pragma unroll
        for (int j = 0; j < 2; ++j)
            bv[j] = *(const half8*)&Bh[wn + j * 16 + fm][ck];
#pragma unroll
        for (int i = 0; i < 4; ++i)
#pragma unroll
            for (int j = 0; j < 2; ++j)
                acc[i][j] = __builtin_amdgcn_mfma_f32_16x16x32_f16(av[i], bv[j], acc[i][j], 0, 0, 0);
        __syncthreads();
    }

#pragma unroll
    for (int i = 0; i < 4; ++i) {
        const int growb = rowA0 + wm + i * 16 + fq * 4;
#pragma unroll
        for (int j = 0; j < 2; ++j) {
            const int gcol = colB0 + wn + j * 16 + fm;
#pragma unroll
            for (int r = 0; r < 4; ++r) {
                float v = acc[i][j][r];
                size_t idx = (size_t)(growb + r) * N + gcol;
                if (OUT_HALF) Ch[idx] = (_Float16)v;
                else          Cf[idx] = v;
            }
        }
    }
}

// ---------------------------------------------------------------------------
// Row softmax over S[SEQ][SEQ] fp32 -> P_hi fp16 in the row's first 8 KB
// (A-stride stays 8192 halfs).
// ---------------------------------------------------------------------------
__global__ __launch_bounds__(256) void softmax_rows_h(float* __restrict__ S) {
    __shared__ float redmax[4];
    __shared__ float redsum[4];
    const int tid = threadIdx.x;
    float* rowp = S + (size_t)blockIdx.x * SEQ;

    float4 v[4];
#pragma unroll
    for (int i = 0; i < 4; ++i)
        v[i] = *(const float4*)(rowp + i * 1024 + (tid << 2));

    float m = -INFINITY;
#pragma unroll
    for (int i = 0; i < 4; ++i)
        m = fmaxf(m, fmaxf(fmaxf(v[i].x, v[i].y), fmaxf(v[i].z, v[i].w)));
#pragma unroll
    for (int off = 32; off > 0; off >>= 1) m = fmaxf(m, __shfl_xor(m, off));
    if ((tid & 63) == 0) redmax[tid >> 6] = m;
    __syncthreads();
    m = fmaxf(fmaxf(redmax[0], redmax[1]), fmaxf(redmax[2], redmax[3]));

    float s = 0.f;
#pragma unroll
    for (int i = 0; i < 4; ++i) {
        v[i].x = expf(v[i].x - m); s += v[i].x;
        v[i].y = expf(v[i].y - m); s += v[i].y;
        v[i].z = expf(v[i].z - m); s += v[i].z;
        v[i].w = expf(v[i].w - m); s += v[i].w;
    }
#pragma unroll
    for (int off = 32; off > 0; off >>= 1) s += __shfl_xor(s, off);
    if ((tid & 63) == 0) redsum[tid >> 6] = s;
    __syncthreads();
    s = redsum[0] + redsum[1] + redsum[2] + redsum[3];

    const float inv = 1.0f / s;
    _Float16* hp = (_Float16*)rowp;
#pragma unroll
    for (int i = 0; i < 4; ++i) {
        half4v h;
        h[0] = (_Float16)(v[i].x * inv);
        h[1] = (_Float16)(v[i].y * inv);
        h[2] = (_Float16)(v[i].z * inv);
        h[3] = (_Float16)(v[i].w * inv);
        *(half4v*)(hp + i * 1024 + (tid << 2)) = h;
    }
}

// ---------------------------------------------------------------------------
// Workspace layout (104 MB used):
//  [0,64M)   S fp32 4096x4096; after softmax row i holds P_hi in first 8 KB.
//            Early (dead before S written): x_hi [0,8M), x_lo [8,16M),
//            wqkT_hi [16,20M), wqkT_lo [20,24M), wvT [24,26M)
//  [64,72M)  Q_hi  [72,80M) Q_lo  [80,88M) K_hi  [88,96M) K_lo  (lda=1024)
//  [96,104M) VT fp16 [1024][4096]
// ---------------------------------------------------------------------------
extern "C" void kernel_launch(void* const* d_in, const int* in_sizes, int n_in,
                              void* d_out, int out_size, void* d_ws, size_t ws_size,
                              hipStream_t stream) {
    const float* x  = (const float*)d_in[0];
    const float* wq = (const float*)d_in[1];
    const float* wk = (const float*)d_in[2];
    const float* wv = (const float*)d_in[3];
    float* out = (float*)d_out;

    char* base = (char*)d_ws;
    const size_t MB = 1u << 20;
    float*    S       = (float*)base;
    _Float16* x_hi    = (_Float16*)(base + 0 * MB);
    _Float16* x_lo    = (_Float16*)(base + 8 * MB);
    _Float16* wqkT_hi = (_Float16*)(base + 16 * MB);   // [2048][1024]
    _Float16* wqkT_lo = (_Float16*)(base + 20 * MB);
    _Float16* wvT     = (_Float16*)(base + 24 * MB);   // [1024][1024]
    _Float16* Q_hi    = (_Float16*)(base + 64 * MB);   // [4096][1024]
    _Float16* Q_lo    = (_Float16*)(base + 72 * MB);
    _Float16* K_hi    = (_Float16*)(base + 80 * MB);
    _Float16* K_lo    = (_Float16*)(base + 88 * MB);
    _Float16* VT      = (_Float16*)(base + 96 * MB);   // [1024][4096]

    // 1) fused prep: 3 transposes + x split, one launch
    prep<<<4096, 256, 0, stream>>>(x, wq, wk, wv, x_hi, x_lo, wqkT_hi, wqkT_lo, wvT);

    // 2) fused Q+K projection (B combined), outputs un-interleaved at lda=1024
    dim3 gqk(2048 / 128, SEQ / 128);   // (16,32) = 512 blocks
    gemm_mfma<1><<<gqk, 256, 0, stream>>>(x_hi, x_lo, DMODEL, wqkT_hi, wqkT_lo, DMODEL,
                                          nullptr, Q_hi, Q_lo, K_hi, K_lo,
                                          2048, DMODEL, 1.0f);
    // V^T = wv^T @ x^T, plain fp16, tile 128x64
    dim3 gvt(SEQ / 64, DMODEL / 128);  // (64,8) = 512 blocks
    gemm_h16_n64<1><<<gvt, 256, 0, stream>>>(wvT, DMODEL, x_hi, DMODEL,
                                             nullptr, VT, SEQ, DMODEL);

    // 3) scores: S = (Q @ K^T) / 32  (3-product split precision, lda=1024)
    dim3 gs(SEQ / 128, SEQ / 128);     // (32,32) = 1024 blocks
    gemm_mfma<0><<<gs, 256, 0, stream>>>(Q_hi, Q_lo, DMODEL, K_hi, K_lo, DMODEL,
                                         S, nullptr, nullptr, nullptr, nullptr,
                                         SEQ, DMODEL, 1.0f / 32.0f);

    // 4) softmax -> P_hi fp16 (in place)
    softmax_rows_h<<<SEQ, 256, 0, stream>>>(S);

    // 5) out = P @ V, plain fp16, tile 128x64
    dim3 go(DMODEL / 64, SEQ / 128);   // (16,32) = 512 blocks
    gemm_h16_n64<0><<<go, 256, 0, stream>>>((_Float16*)S, 2 * SEQ, VT, SEQ,
                                            out, nullptr, DMODEL, SEQ);
}